// Round 1
// baseline (1475.349 us; speedup 1.0000x reference)
//
#include <hip/hip_runtime.h>
#include <cstdint>
#include <cstddef>

typedef unsigned short ushort_t;
typedef __attribute__((ext_vector_type(8))) short bf16x8;
typedef __attribute__((ext_vector_type(4))) float f32x4;

#define T_TOKENS 8192
#define DIM      1024
#define NEXP     16

// ---------- helpers ----------
static __device__ __forceinline__ unsigned short f2bf(float f) {
  union { float f; unsigned u; } v; v.f = f;
  unsigned r = v.u + 0x7FFFu + ((v.u >> 16) & 1u);   // round-to-nearest-even
  return (unsigned short)(r >> 16);
}

static __device__ __forceinline__ void gload16(const void* g, void* l) {
  __builtin_amdgcn_global_load_lds(
      (const __attribute__((address_space(1))) unsigned int*)g,
      (__attribute__((address_space(3))) unsigned int*)l, 16, 0, 0);
}

static __device__ __forceinline__ bf16x8 pack8(float4 a, float4 b) {
  bf16x8 v;
  v[0]=(short)f2bf(a.x); v[1]=(short)f2bf(a.y); v[2]=(short)f2bf(a.z); v[3]=(short)f2bf(a.w);
  v[4]=(short)f2bf(b.x); v[5]=(short)f2bf(b.y); v[6]=(short)f2bf(b.z); v[7]=(short)f2bf(b.w);
  return v;
}

// ---------- x -> bf16 ----------
__global__ __launch_bounds__(256) void k_cvt(const float* __restrict__ in,
                                             ushort_t* __restrict__ outp) {
  int i = (blockIdx.x * 256 + threadIdx.x) * 4;
  float4 v = *(const float4*)(in + i);
  ushort4 o;
  o.x = f2bf(v.x); o.y = f2bf(v.y); o.z = f2bf(v.z); o.w = f2bf(v.w);
  *(ushort4*)(outp + i) = o;
}

// ---------- gate: fp32 scores, top-2, expert lists ----------
__global__ __launch_bounds__(64) void k_gate(const float* __restrict__ x,
                                             const float* __restrict__ gw,
                                             int* __restrict__ cnt,
                                             float* __restrict__ probs,
                                             int* __restrict__ toklist,
                                             float* __restrict__ wlist) {
  int t = blockIdx.x;
  int lane = threadIdx.x;
  float xv[16];
  const float* xr = x + (size_t)t * DIM + lane * 16;
#pragma unroll
  for (int j = 0; j < 16; j += 4) {
    float4 v = *(const float4*)(xr + j);
    xv[j] = v.x; xv[j+1] = v.y; xv[j+2] = v.z; xv[j+3] = v.w;
  }
  float sc[NEXP];
#pragma unroll
  for (int e = 0; e < NEXP; e++) {
    const float* gr = gw + (size_t)e * DIM + lane * 16;
    float a = 0.f;
#pragma unroll
    for (int j = 0; j < 16; j += 4) {
      float4 g = *(const float4*)(gr + j);
      a += xv[j]*g.x + xv[j+1]*g.y + xv[j+2]*g.z + xv[j+3]*g.w;
    }
#pragma unroll
    for (int o = 32; o > 0; o >>= 1) a += __shfl_xor(a, o, 64);
    sc[e] = 1.f / (1.f + expf(-a));
  }
  if (lane == 0) {
    float best = -1e30f, sec = -1e30f;
    int bi = 0, si = 0;
#pragma unroll
    for (int e = 0; e < NEXP; e++) {
      float s = sc[e];
      if (s > best) { sec = best; si = bi; best = s; bi = e; }
      else if (s > sec) { sec = s; si = e; }
    }
    float inv = 1.f / (best + sec);
    float w0 = best * inv, w1 = sec * inv;
    int p0 = atomicAdd(&cnt[bi], 1);
    toklist[bi * T_TOKENS + p0] = t; wlist[bi * T_TOKENS + p0] = w0;
    int p1 = atomicAdd(&cnt[si], 1);
    toklist[si * T_TOKENS + p1] = t; wlist[si * T_TOKENS + p1] = w1;
    atomicAdd(&probs[bi], w0);
    atomicAdd(&probs[si], w1);
  }
}

// ---------- prefix offsets + aux loss ----------
__global__ void k_offsets(const int* __restrict__ cnt, const float* __restrict__ probs,
                          int* __restrict__ seg, float* __restrict__ loss_out) {
  if (threadIdx.x == 0 && blockIdx.x == 0) {
    int acc = 0;
    float L = 0.f;
    for (int e = 0; e < NEXP; e++) {
      seg[e] = acc; acc += cnt[e];
      float f = 16.f * (float)cnt[e] / (2.f * 8192.f);
      L += f * (probs[e] / 8192.f);
    }
    seg[NEXP] = acc;
    *loss_out = L;
  }
}

// ---------- GEMM1: h = silu(X W1^T + b1) * (X W3^T + b3) -> P (bf16) ----------
// tile 128 x 64 (per B-matrix), BK=32, 4 waves (2x2), dual accumulator
__global__ __launch_bounds__(256) void k_gemm1(
    const ushort_t* __restrict__ X,
    const float* __restrict__ W1f, const float* __restrict__ W3f,
    const float* __restrict__ b1, const float* __restrict__ b3,
    ushort_t* __restrict__ P, int ldP,
    const int* __restrict__ toklist, const int* __restrict__ cnt,
    const int* __restrict__ seg) {
  __shared__ __align__(16) ushort_t As[128 * 32];
  __shared__ __align__(16) ushort_t B1s[64 * 32];
  __shared__ __align__(16) ushort_t B3s[64 * 32];

  const int tid = threadIdx.x;
  const int lane = tid & 63, wave = tid >> 6;
  const int wm = wave >> 1, wn = wave & 1;
  const int rb = blockIdx.x, cb = blockIdx.y, e = blockIdx.z;

  int Ne, pbase;
  const int* tl = nullptr;
  const float* W1 = W1f;
  const float* W3 = W3f;
  if (cnt) {
    Ne = cnt[e];
    if (rb * 128 >= Ne) return;
    pbase = seg[e];
    tl = toklist + e * T_TOKENS;
    W1 += (size_t)e * 1024 * 1024;
    W3 += (size_t)e * 1024 * 1024;
  } else { Ne = T_TOKENS; pbase = 0; }

  // A staging: 8 chunks of 512 bf16; wave handles chunks 2w, 2w+1
  const int c0 = wave * 2, c1 = wave * 2 + 1;
  const int colA = (lane & 3) * 8;
  const int r0 = c0 * 16 + (lane >> 2), r1 = c1 * 16 + (lane >> 2);
  const int gr0 = rb * 128 + r0, gr1 = rb * 128 + r1;
  const int sr0 = tl ? tl[min(gr0, Ne - 1)] : gr0;
  const int sr1 = tl ? tl[min(gr1, Ne - 1)] : gr1;
  const ushort_t* ap0 = X + (size_t)sr0 * DIM + colA;
  const ushort_t* ap1 = X + (size_t)sr1 * DIM + colA;
  ushort_t* ad0 = As + c0 * 512;
  ushort_t* ad1 = As + c1 * 512;

  // B staging (fp32 -> bf16): thread covers 8 elems, row=tid/4, col=(tid&3)*8
  const int brow = tid >> 2, bcol = (tid & 3) * 8;
  const float* w1p = W1 + (size_t)(cb * 64 + brow) * DIM + bcol;
  const float* w3p = W3 + (size_t)(cb * 64 + brow) * DIM + bcol;
  ushort_t* b1dst = B1s + tid * 8;
  ushort_t* b3dst = B3s + tid * 8;

  f32x4 acc1[4][2], acc3[4][2];
#pragma unroll
  for (int m = 0; m < 4; m++)
#pragma unroll
    for (int n = 0; n < 2; n++) {
      acc1[m][n] = (f32x4){0.f, 0.f, 0.f, 0.f};
      acc3[m][n] = (f32x4){0.f, 0.f, 0.f, 0.f};
    }

  for (int kk = 0; kk < 32; ++kk) {
    const int k0 = kk * 32;
    gload16(ap0 + k0, ad0);
    gload16(ap1 + k0, ad1);
    float4 f0 = *(const float4*)(w1p + k0);
    float4 f1 = *(const float4*)(w1p + k0 + 4);
    float4 g0 = *(const float4*)(w3p + k0);
    float4 g1 = *(const float4*)(w3p + k0 + 4);
    *(bf16x8*)b1dst = pack8(f0, f1);
    *(bf16x8*)b3dst = pack8(g0, g1);
    __syncthreads();

    const int koff = (lane >> 4) * 8;
    bf16x8 af[4], bfr1[2], bfr3[2];
#pragma unroll
    for (int m = 0; m < 4; m++) {
      int row = wm * 64 + m * 16 + (lane & 15);
      af[m] = *(const bf16x8*)(As + row * 32 + koff);
    }
#pragma unroll
    for (int n = 0; n < 2; n++) {
      int rbb = wn * 32 + n * 16 + (lane & 15);
      bfr1[n] = *(const bf16x8*)(B1s + rbb * 32 + koff);
      bfr3[n] = *(const bf16x8*)(B3s + rbb * 32 + koff);
    }
#pragma unroll
    for (int m = 0; m < 4; m++)
#pragma unroll
      for (int n = 0; n < 2; n++) {
        acc1[m][n] = __builtin_amdgcn_mfma_f32_16x16x32_bf16(af[m], bfr1[n], acc1[m][n], 0, 0, 0);
        acc3[m][n] = __builtin_amdgcn_mfma_f32_16x16x32_bf16(af[m], bfr3[n], acc3[m][n], 0, 0, 0);
      }
    __syncthreads();
  }

  // epilogue: silu(h1)*h3 -> bf16 P
  const int colbase = cb * 64 + wn * 32;
#pragma unroll
  for (int n = 0; n < 2; n++) {
    int col = colbase + n * 16 + (lane & 15);
    float bb1 = b1 ? b1[col] : 0.f;
    float bb3 = b3 ? b3[col] : 0.f;
#pragma unroll
    for (int m = 0; m < 4; m++) {
#pragma unroll
      for (int r = 0; r < 4; r++) {
        int row = rb * 128 + wm * 64 + m * 16 + (lane >> 4) * 4 + r;
        if (row < Ne) {
          float h1 = acc1[m][n][r] + bb1;
          float h3 = acc3[m][n][r] + bb3;
          float pv = (h1 / (1.f + expf(-h1))) * h3;
          P[(size_t)(pbase + row) * ldP + col] = f2bf(pv);
        }
      }
    }
  }
}

// ---------- GEMM2: out = P W2^T (+b2 | *wgt scatter-add) ----------
// tile 128 x 128, BK=32, 4 waves (2x2)
__global__ __launch_bounds__(256) void k_gemm2(
    const ushort_t* __restrict__ Pbuf, const float* __restrict__ W2f,
    const float* __restrict__ b2,
    float* __restrict__ outp,
    const int* __restrict__ toklist, const float* __restrict__ wlist,
    const int* __restrict__ cnt, const int* __restrict__ seg, int Kd) {
  __shared__ __align__(16) ushort_t As[128 * 32];
  __shared__ __align__(16) ushort_t Bs[128 * 32];

  const int tid = threadIdx.x;
  const int lane = tid & 63, wave = tid >> 6;
  const int wm = wave >> 1, wn = wave & 1;
  const int rb = blockIdx.x, cb = blockIdx.y, e = blockIdx.z;

  int Ne;
  const ushort_t* A;
  const float* W2 = W2f;
  const int* tl = nullptr; const float* wl = nullptr;
  if (cnt) {
    Ne = cnt[e];
    if (rb * 128 >= Ne) return;
    A = Pbuf + (size_t)seg[e] * Kd;
    W2 += (size_t)e * 1024 * Kd;
    tl = toklist + e * T_TOKENS;
    wl = wlist + e * T_TOKENS;
  } else { Ne = T_TOKENS; A = Pbuf; }

  const int c0 = wave * 2, c1 = wave * 2 + 1;
  const int colA = (lane & 3) * 8;
  const int r0 = c0 * 16 + (lane >> 2), r1 = c1 * 16 + (lane >> 2);
  const int sr0 = min(rb * 128 + r0, Ne - 1);
  const int sr1 = min(rb * 128 + r1, Ne - 1);
  const ushort_t* ap0 = A + (size_t)sr0 * Kd + colA;
  const ushort_t* ap1 = A + (size_t)sr1 * Kd + colA;
  ushort_t* ad0 = As + c0 * 512;
  ushort_t* ad1 = As + c1 * 512;

  // B staging: thread covers 16 elems: row=tid/2, col=(tid&1)*16
  const int brow = tid >> 1, bcol = (tid & 1) * 16;
  const float* wp = W2 + (size_t)(cb * 128 + brow) * Kd + bcol;
  ushort_t* bdst = Bs + tid * 16;

  f32x4 acc[4][4];
#pragma unroll
  for (int m = 0; m < 4; m++)
#pragma unroll
    for (int n = 0; n < 4; n++) acc[m][n] = (f32x4){0.f, 0.f, 0.f, 0.f};

  const int ksteps = Kd >> 5;
  for (int kk = 0; kk < ksteps; ++kk) {
    const int k0 = kk * 32;
    gload16(ap0 + k0, ad0);
    gload16(ap1 + k0, ad1);
    float4 a0 = *(const float4*)(wp + k0);
    float4 a1 = *(const float4*)(wp + k0 + 4);
    float4 a2 = *(const float4*)(wp + k0 + 8);
    float4 a3 = *(const float4*)(wp + k0 + 12);
    *(bf16x8*)(bdst) = pack8(a0, a1);
    *(bf16x8*)(bdst + 8) = pack8(a2, a3);
    __syncthreads();

    const int koff = (lane >> 4) * 8;
    bf16x8 af[4], bf[4];
#pragma unroll
    for (int m = 0; m < 4; m++) {
      int row = wm * 64 + m * 16 + (lane & 15);
      af[m] = *(const bf16x8*)(As + row * 32 + koff);
    }
#pragma unroll
    for (int n = 0; n < 4; n++) {
      int rbb = wn * 64 + n * 16 + (lane & 15);
      bf[n] = *(const bf16x8*)(Bs + rbb * 32 + koff);
    }
#pragma unroll
    for (int m = 0; m < 4; m++)
#pragma unroll
      for (int n = 0; n < 4; n++)
        acc[m][n] = __builtin_amdgcn_mfma_f32_16x16x32_bf16(af[m], bf[n], acc[m][n], 0, 0, 0);
    __syncthreads();
  }

#pragma unroll
  for (int n = 0; n < 4; n++) {
    int col = cb * 128 + wn * 64 + n * 16 + (lane & 15);
    float bias = b2 ? b2[col] : 0.f;
#pragma unroll
    for (int m = 0; m < 4; m++) {
#pragma unroll
      for (int r = 0; r < 4; r++) {
        int rl = rb * 128 + wm * 64 + m * 16 + (lane >> 4) * 4 + r;
        if (cnt) {
          if (rl < Ne) {
            int tok = tl[rl];
            float wgt = wl[rl];
            atomicAdd(outp + (size_t)tok * DIM + col, acc[m][n][r] * wgt);
          }
        } else {
          outp[(size_t)rl * DIM + col] = acc[m][n][r] + bias;
        }
      }
    }
  }
}

// ---------- launch ----------
extern "C" void kernel_launch(void* const* d_in, const int* in_sizes, int n_in,
                              void* d_out, int out_size, void* d_ws, size_t ws_size,
                              hipStream_t stream) {
  const float* x   = (const float*)d_in[0];
  const float* gw  = (const float*)d_in[1];
  const float* w1  = (const float*)d_in[2];
  const float* w2  = (const float*)d_in[3];
  const float* w3  = (const float*)d_in[4];
  const float* sw1 = (const float*)d_in[5];
  const float* sb1 = (const float*)d_in[6];
  const float* sw2 = (const float*)d_in[7];
  const float* sb2 = (const float*)d_in[8];
  const float* sw3 = (const float*)d_in[9];
  const float* sb3 = (const float*)d_in[10];
  float* out  = (float*)d_out;
  float* loss = out + (size_t)T_TOKENS * DIM;

  char* w = (char*)d_ws;
  ushort_t* p_buf = (ushort_t*)w; w += (size_t)33554432 + 262144;  // 16384x1024 bf16 (== 8192x2048) + slack
  ushort_t* x_bf  = (ushort_t*)w; w += (size_t)T_TOKENS * DIM * 2; // 16 MB
  int*   toklist  = (int*)w;      w += (size_t)NEXP * T_TOKENS * 4;
  float* wlist    = (float*)w;    w += (size_t)NEXP * T_TOKENS * 4;
  int*   cnt      = (int*)w;      w += 64;
  float* probs    = (float*)w;    w += 64;
  int*   seg      = (int*)w;      w += 128;

  hipMemsetAsync(cnt, 0, 64 + 64 + 128, stream);

  k_cvt<<<T_TOKENS * DIM / (256 * 4), 256, 0, stream>>>(x, x_bf);
  k_gate<<<T_TOKENS, 64, 0, stream>>>(x, gw, cnt, probs, toklist, wlist);
  k_offsets<<<1, 64, 0, stream>>>(cnt, probs, seg, loss);

  // shared expert: p = silu(x sw1^T + b1) * (x sw3^T + b3); out = p sw2^T + b2
  k_gemm1<<<dim3(64, 32, 1), 256, 0, stream>>>(x_bf, sw1, sw3, sb1, sb3,
                                               p_buf, 2048, nullptr, nullptr, nullptr);
  k_gemm2<<<dim3(64, 8, 1), 256, 0, stream>>>(p_buf, sw2, sb2, out,
                                              nullptr, nullptr, nullptr, nullptr, 2048);

  // routed experts (gathered rows, weighted scatter-add)
  k_gemm1<<<dim3(64, 16, NEXP), 256, 0, stream>>>(x_bf, w1, w3, nullptr, nullptr,
                                                  p_buf, 1024, toklist, cnt, seg);
  k_gemm2<<<dim3(64, 8, NEXP), 256, 0, stream>>>(p_buf, w2, nullptr, out,
                                                 toklist, wlist, cnt, seg, 1024);
}

// Round 2
// 1163.733 us; speedup vs baseline: 1.2678x; 1.2678x over previous
//
#include <hip/hip_runtime.h>
#include <cstdint>
#include <cstddef>

typedef unsigned short ushort_t;
typedef __attribute__((ext_vector_type(8))) short bf16x8;
typedef __attribute__((ext_vector_type(8))) unsigned short u16x8;
typedef __attribute__((ext_vector_type(4))) float f32x4;

#define T_TOKENS 8192
#define DIM      1024
#define NEXP     16

// ---------- helpers ----------
static __device__ __forceinline__ unsigned short f2bf(float f) {
  union { float f; unsigned u; } v; v.f = f;
  unsigned r = v.u + 0x7FFFu + ((v.u >> 16) & 1u);   // round-to-nearest-even
  return (unsigned short)(r >> 16);
}

static __device__ __forceinline__ void gload16(const void* g, void* l) {
  __builtin_amdgcn_global_load_lds(
      (const __attribute__((address_space(1))) unsigned int*)g,
      (__attribute__((address_space(3))) unsigned int*)l, 16, 0, 0);
}

// ---------- fp32 -> bf16, 8 elems/thread ----------
__global__ __launch_bounds__(256) void k_cvt8(const float* __restrict__ in,
                                              ushort_t* __restrict__ outp) {
  size_t i = ((size_t)blockIdx.x * 256 + threadIdx.x) * 8;
  float4 a = *(const float4*)(in + i);
  float4 b = *(const float4*)(in + i + 4);
  u16x8 o;
  o[0]=f2bf(a.x); o[1]=f2bf(a.y); o[2]=f2bf(a.z); o[3]=f2bf(a.w);
  o[4]=f2bf(b.x); o[5]=f2bf(b.y); o[6]=f2bf(b.z); o[7]=f2bf(b.w);
  *(u16x8*)(outp + i) = o;
}

// ---------- gate: fp32 scores, top-2, expert lists ----------
__global__ __launch_bounds__(64) void k_gate(const float* __restrict__ x,
                                             const float* __restrict__ gw,
                                             int* __restrict__ cnt,
                                             float* __restrict__ probs,
                                             int* __restrict__ toklist,
                                             float* __restrict__ wlist) {
  int t = blockIdx.x;
  int lane = threadIdx.x;
  float xv[16];
  const float* xr = x + (size_t)t * DIM + lane * 16;
#pragma unroll
  for (int j = 0; j < 16; j += 4) {
    float4 v = *(const float4*)(xr + j);
    xv[j] = v.x; xv[j+1] = v.y; xv[j+2] = v.z; xv[j+3] = v.w;
  }
  float sc[NEXP];
#pragma unroll
  for (int e = 0; e < NEXP; e++) {
    const float* gr = gw + (size_t)e * DIM + lane * 16;
    float a = 0.f;
#pragma unroll
    for (int j = 0; j < 16; j += 4) {
      float4 g = *(const float4*)(gr + j);
      a += xv[j]*g.x + xv[j+1]*g.y + xv[j+2]*g.z + xv[j+3]*g.w;
    }
#pragma unroll
    for (int o = 32; o > 0; o >>= 1) a += __shfl_xor(a, o, 64);
    sc[e] = 1.f / (1.f + expf(-a));
  }
  if (lane == 0) {
    float best = -1e30f, sec = -1e30f;
    int bi = 0, si = 0;
#pragma unroll
    for (int e = 0; e < NEXP; e++) {
      float s = sc[e];
      if (s > best) { sec = best; si = bi; best = s; bi = e; }
      else if (s > sec) { sec = s; si = e; }
    }
    float inv = 1.f / (best + sec);
    float w0 = best * inv, w1 = sec * inv;
    int p0 = atomicAdd(&cnt[bi], 1);
    toklist[bi * T_TOKENS + p0] = t; wlist[bi * T_TOKENS + p0] = w0;
    int p1 = atomicAdd(&cnt[si], 1);
    toklist[si * T_TOKENS + p1] = t; wlist[si * T_TOKENS + p1] = w1;
    atomicAdd(&probs[bi], w0);
    atomicAdd(&probs[si], w1);
  }
}

// ---------- prefix offsets + aux loss ----------
__global__ void k_offsets(const int* __restrict__ cnt, const float* __restrict__ probs,
                          int* __restrict__ seg, float* __restrict__ loss_out) {
  if (threadIdx.x == 0 && blockIdx.x == 0) {
    int acc = 0;
    float L = 0.f;
    for (int e = 0; e < NEXP; e++) {
      seg[e] = acc; acc += cnt[e];
      float f = 16.f * (float)cnt[e] / (2.f * 8192.f);
      L += f * (probs[e] / 8192.f);
    }
    seg[NEXP] = acc;
    *loss_out = L;
  }
}

// ---------- GEMM1: h = silu(X W1^T + b1) * (X W3^T + b3) -> P (bf16) ----------
// tile 128 rows x 128 inter-cols, BK=32, 4 waves (2x2), dual-B, all-bf16,
// all tiles staged via global_load_lds width=16 (m97 structure).
__global__ __launch_bounds__(256, 2) void k_gemm1(
    const ushort_t* __restrict__ X,
    const ushort_t* __restrict__ W1b, const ushort_t* __restrict__ W3b,
    const float* __restrict__ b1, const float* __restrict__ b3,
    ushort_t* __restrict__ P, int ldP,
    const int* __restrict__ toklist, const int* __restrict__ cnt,
    const int* __restrict__ seg) {
  __shared__ __align__(16) ushort_t As[128 * 32];
  __shared__ __align__(16) ushort_t B1s[128 * 32];
  __shared__ __align__(16) ushort_t B3s[128 * 32];

  const int tid = threadIdx.x;
  const int lane = tid & 63, wave = tid >> 6;
  const int wm = wave >> 1, wn = wave & 1;
  const int rb = blockIdx.x, cb = blockIdx.y, e = blockIdx.z;

  int Ne, pbase;
  const int* tl = nullptr;
  const ushort_t* W1 = W1b;
  const ushort_t* W3 = W3b;
  if (cnt) {
    Ne = cnt[e];
    if (rb * 128 >= Ne) return;
    pbase = seg[e];
    tl = toklist + e * T_TOKENS;
    W1 += (size_t)e * 1024 * 1024;
    W3 += (size_t)e * 1024 * 1024;
  } else { Ne = T_TOKENS; pbase = 0; }

  // staging geometry: chunk = 16 rows x 32 cols (1KB). wave w covers chunks 2w,2w+1.
  const int c0 = wave * 2, c1 = c0 + 1;
  const int lrow = lane >> 2;          // 0..15
  const int lcol = (lane & 3) * 8;     // elem col within 32

  const int ar0 = rb * 128 + c0 * 16 + lrow;
  const int ar1 = rb * 128 + c1 * 16 + lrow;
  const int sr0 = tl ? tl[min(ar0, Ne - 1)] : ar0;
  const int sr1 = tl ? tl[min(ar1, Ne - 1)] : ar1;
  const ushort_t* apA0 = X + (size_t)sr0 * DIM + lcol;
  const ushort_t* apA1 = X + (size_t)sr1 * DIM + lcol;
  ushort_t* dA0 = As + c0 * 512;
  ushort_t* dA1 = As + c1 * 512;

  const int br0 = cb * 128 + c0 * 16 + lrow;
  const int br1 = cb * 128 + c1 * 16 + lrow;
  const ushort_t* bp10 = W1 + (size_t)br0 * DIM + lcol;
  const ushort_t* bp11 = W1 + (size_t)br1 * DIM + lcol;
  const ushort_t* bp30 = W3 + (size_t)br0 * DIM + lcol;
  const ushort_t* bp31 = W3 + (size_t)br1 * DIM + lcol;
  ushort_t* dB10 = B1s + c0 * 512;
  ushort_t* dB11 = B1s + c1 * 512;
  ushort_t* dB30 = B3s + c0 * 512;
  ushort_t* dB31 = B3s + c1 * 512;

  f32x4 acc1[4][4], acc3[4][4];
#pragma unroll
  for (int m = 0; m < 4; m++)
#pragma unroll
    for (int n = 0; n < 4; n++) {
      acc1[m][n] = (f32x4){0.f, 0.f, 0.f, 0.f};
      acc3[m][n] = (f32x4){0.f, 0.f, 0.f, 0.f};
    }

  const int koff = (lane >> 4) * 8;
  for (int kk = 0; kk < 32; ++kk) {
    const int k0 = kk * 32;
    gload16(apA0 + k0, dA0);
    gload16(apA1 + k0, dA1);
    gload16(bp10 + k0, dB10);
    gload16(bp11 + k0, dB11);
    gload16(bp30 + k0, dB30);
    gload16(bp31 + k0, dB31);
    __syncthreads();

    bf16x8 af[4], b1f[4], b3f[4];
#pragma unroll
    for (int m = 0; m < 4; m++) {
      int row = wm * 64 + m * 16 + (lane & 15);
      af[m] = *(const bf16x8*)(As + row * 32 + koff);
    }
#pragma unroll
    for (int n = 0; n < 4; n++) {
      int rbb = wn * 64 + n * 16 + (lane & 15);
      b1f[n] = *(const bf16x8*)(B1s + rbb * 32 + koff);
      b3f[n] = *(const bf16x8*)(B3s + rbb * 32 + koff);
    }
#pragma unroll
    for (int m = 0; m < 4; m++)
#pragma unroll
      for (int n = 0; n < 4; n++) {
        acc1[m][n] = __builtin_amdgcn_mfma_f32_16x16x32_bf16(af[m], b1f[n], acc1[m][n], 0, 0, 0);
        acc3[m][n] = __builtin_amdgcn_mfma_f32_16x16x32_bf16(af[m], b3f[n], acc3[m][n], 0, 0, 0);
      }
    __syncthreads();
  }

  // epilogue: silu(h1)*h3 -> bf16 P
#pragma unroll
  for (int n = 0; n < 4; n++) {
    int col = cb * 128 + wn * 64 + n * 16 + (lane & 15);
    float bb1 = b1 ? b1[col] : 0.f;
    float bb3 = b3 ? b3[col] : 0.f;
#pragma unroll
    for (int m = 0; m < 4; m++) {
#pragma unroll
      for (int r = 0; r < 4; r++) {
        int row = rb * 128 + wm * 64 + m * 16 + (lane >> 4) * 4 + r;
        if (row < Ne) {
          float h1 = acc1[m][n][r] + bb1;
          float h3 = acc3[m][n][r] + bb3;
          float pv = (h1 / (1.f + expf(-h1))) * h3;
          P[(size_t)(pbase + row) * ldP + col] = f2bf(pv);
        }
      }
    }
  }
}

// ---------- GEMM2: out = P W2^T (+b2 | *wgt scatter-add) ----------
// m97 structure: tile 128 x 128, BK=32, 4 waves (2x2), bf16 B via gload_lds
__global__ __launch_bounds__(256, 2) void k_gemm2(
    const ushort_t* __restrict__ Pbuf, const ushort_t* __restrict__ W2b,
    const float* __restrict__ b2,
    float* __restrict__ outp,
    const int* __restrict__ toklist, const float* __restrict__ wlist,
    const int* __restrict__ cnt, const int* __restrict__ seg, int Kd) {
  __shared__ __align__(16) ushort_t As[128 * 32];
  __shared__ __align__(16) ushort_t Bs[128 * 32];

  const int tid = threadIdx.x;
  const int lane = tid & 63, wave = tid >> 6;
  const int wm = wave >> 1, wn = wave & 1;
  const int rb = blockIdx.x, cb = blockIdx.y, e = blockIdx.z;

  int Ne;
  const ushort_t* A;
  const ushort_t* W2 = W2b;
  const int* tl = nullptr; const float* wl = nullptr;
  if (cnt) {
    Ne = cnt[e];
    if (rb * 128 >= Ne) return;
    A = Pbuf + (size_t)seg[e] * Kd;
    W2 += (size_t)e * 1024 * Kd;
    tl = toklist + e * T_TOKENS;
    wl = wlist + e * T_TOKENS;
  } else { Ne = T_TOKENS; A = Pbuf; }

  const int c0 = wave * 2, c1 = c0 + 1;
  const int lrow = lane >> 2;
  const int lcol = (lane & 3) * 8;

  const int sr0 = min(rb * 128 + c0 * 16 + lrow, Ne - 1);
  const int sr1 = min(rb * 128 + c1 * 16 + lrow, Ne - 1);
  const ushort_t* apA0 = A + (size_t)sr0 * Kd + lcol;
  const ushort_t* apA1 = A + (size_t)sr1 * Kd + lcol;
  ushort_t* dA0 = As + c0 * 512;
  ushort_t* dA1 = As + c1 * 512;

  const int br0 = cb * 128 + c0 * 16 + lrow;
  const int br1 = cb * 128 + c1 * 16 + lrow;
  const ushort_t* bp0 = W2 + (size_t)br0 * Kd + lcol;
  const ushort_t* bp1 = W2 + (size_t)br1 * Kd + lcol;
  ushort_t* dB0 = Bs + c0 * 512;
  ushort_t* dB1 = Bs + c1 * 512;

  f32x4 acc[4][4];
#pragma unroll
  for (int m = 0; m < 4; m++)
#pragma unroll
    for (int n = 0; n < 4; n++) acc[m][n] = (f32x4){0.f, 0.f, 0.f, 0.f};

  const int koff = (lane >> 4) * 8;
  const int ksteps = Kd >> 5;
  for (int kk = 0; kk < ksteps; ++kk) {
    const int k0 = kk * 32;
    gload16(apA0 + k0, dA0);
    gload16(apA1 + k0, dA1);
    gload16(bp0 + k0, dB0);
    gload16(bp1 + k0, dB1);
    __syncthreads();

    bf16x8 af[4], bf[4];
#pragma unroll
    for (int m = 0; m < 4; m++) {
      int row = wm * 64 + m * 16 + (lane & 15);
      af[m] = *(const bf16x8*)(As + row * 32 + koff);
    }
#pragma unroll
    for (int n = 0; n < 4; n++) {
      int rbb = wn * 64 + n * 16 + (lane & 15);
      bf[n] = *(const bf16x8*)(Bs + rbb * 32 + koff);
    }
#pragma unroll
    for (int m = 0; m < 4; m++)
#pragma unroll
      for (int n = 0; n < 4; n++)
        acc[m][n] = __builtin_amdgcn_mfma_f32_16x16x32_bf16(af[m], bf[n], acc[m][n], 0, 0, 0);
    __syncthreads();
  }

#pragma unroll
  for (int n = 0; n < 4; n++) {
    int col = cb * 128 + wn * 64 + n * 16 + (lane & 15);
    float bias = b2 ? b2[col] : 0.f;
#pragma unroll
    for (int m = 0; m < 4; m++) {
#pragma unroll
      for (int r = 0; r < 4; r++) {
        int rl = rb * 128 + wm * 64 + m * 16 + (lane >> 4) * 4 + r;
        if (cnt) {
          if (rl < Ne) {
            int tok = tl[rl];
            float wgt = wl[rl];
            atomicAdd(outp + (size_t)tok * DIM + col, acc[m][n][r] * wgt);
          }
        } else {
          outp[(size_t)rl * DIM + col] = acc[m][n][r] + bias;
        }
      }
    }
  }
}

// ---------- launch ----------
extern "C" void kernel_launch(void* const* d_in, const int* in_sizes, int n_in,
                              void* d_out, int out_size, void* d_ws, size_t ws_size,
                              hipStream_t stream) {
  const float* x   = (const float*)d_in[0];
  const float* gw  = (const float*)d_in[1];
  const float* w1  = (const float*)d_in[2];
  const float* w2  = (const float*)d_in[3];
  const float* w3  = (const float*)d_in[4];
  const float* sw1 = (const float*)d_in[5];
  const float* sb1 = (const float*)d_in[6];
  const float* sw2 = (const float*)d_in[7];
  const float* sb2 = (const float*)d_in[8];
  const float* sw3 = (const float*)d_in[9];
  const float* sb3 = (const float*)d_in[10];
  float* out  = (float*)d_out;
  float* loss = out + (size_t)T_TOKENS * DIM;

  const size_t NW = (size_t)NEXP * 1024 * 1024;   // 16.78M elems per routed weight
  const size_t NS = (size_t)2048 * 1024;          // 2.10M elems per shared weight

  char* w = (char*)d_ws;
  ushort_t* w1b  = (ushort_t*)w; w += NW * 2;
  ushort_t* w2b  = (ushort_t*)w; w += NW * 2;
  ushort_t* w3b  = (ushort_t*)w; w += NW * 2;
  ushort_t* sw1b = (ushort_t*)w; w += NS * 2;
  ushort_t* sw2b = (ushort_t*)w; w += NS * 2;
  ushort_t* sw3b = (ushort_t*)w; w += NS * 2;
  ushort_t* p_buf = (ushort_t*)w; w += (size_t)33554432 + 262144; // 16384x1024 bf16 (== 8192x2048) + slack
  ushort_t* x_bf  = (ushort_t*)w; w += (size_t)T_TOKENS * DIM * 2;
  int*   toklist  = (int*)w;      w += (size_t)NEXP * T_TOKENS * 4;
  float* wlist    = (float*)w;    w += (size_t)NEXP * T_TOKENS * 4;
  int*   cnt      = (int*)w;      w += 64;
  float* probs    = (float*)w;    w += 64;
  int*   seg      = (int*)w;      w += 128;

  hipMemsetAsync(cnt, 0, 64 + 64 + 128, stream);

  // fp32 -> bf16 conversions (8 elems/thread)
  k_cvt8<<<(T_TOKENS * DIM) / 2048, 256, 0, stream>>>(x, x_bf);
  k_cvt8<<<NW / 2048, 256, 0, stream>>>(w1, w1b);
  k_cvt8<<<NW / 2048, 256, 0, stream>>>(w2, w2b);
  k_cvt8<<<NW / 2048, 256, 0, stream>>>(w3, w3b);
  k_cvt8<<<NS / 2048, 256, 0, stream>>>(sw1, sw1b);
  k_cvt8<<<NS / 2048, 256, 0, stream>>>(sw2, sw2b);
  k_cvt8<<<NS / 2048, 256, 0, stream>>>(sw3, sw3b);

  k_gate<<<T_TOKENS, 64, 0, stream>>>(x, gw, cnt, probs, toklist, wlist);
  k_offsets<<<1, 64, 0, stream>>>(cnt, probs, seg, loss);

  // shared expert: p = silu(x sw1^T + b1) * (x sw3^T + b3); out = p sw2^T + b2
  k_gemm1<<<dim3(64, 16, 1), 256, 0, stream>>>(x_bf, sw1b, sw3b, sb1, sb3,
                                               p_buf, 2048, nullptr, nullptr, nullptr);
  k_gemm2<<<dim3(64, 8, 1), 256, 0, stream>>>(p_buf, sw2b, sb2, out,
                                              nullptr, nullptr, nullptr, nullptr, 2048);

  // routed experts (gathered rows, weighted scatter-add)
  k_gemm1<<<dim3(64, 8, NEXP), 256, 0, stream>>>(x_bf, w1b, w3b, nullptr, nullptr,
                                                 p_buf, 1024, toklist, cnt, seg);
  k_gemm2<<<dim3(64, 8, NEXP), 256, 0, stream>>>(p_buf, w2b, nullptr, out,
                                                 toklist, wlist, cnt, seg, 1024);
}